// Round 7
// baseline (396.451 us; speedup 1.0000x reference)
//
#include <hip/hip_runtime.h>
#include <math.h>

#define BS 8
#define NQ 1200
#define NV 19560
#define EMB 256
#define TPB 153                 // 128-row tiles per batch (153*128 = 19584 >= NV)

typedef __bf16 bf16;
typedef bf16 bf16x8 __attribute__((ext_vector_type(8)));
typedef float f32x4 __attribute__((ext_vector_type(4)));
typedef float f32x16 __attribute__((ext_vector_type(16)));

static __device__ __forceinline__ bf16x8 cvt8(float4 a, float4 b) {
    bf16x8 r;
    r[0] = (bf16)a.x; r[1] = (bf16)a.y; r[2] = (bf16)a.z; r[3] = (bf16)a.w;
    r[4] = (bf16)b.x; r[5] = (bf16)b.y; r[6] = (bf16)b.z; r[7] = (bf16)b.w;
    return r;
}

// async 16B global -> LDS (wave-uniform LDS base + lane*16 in HW; global src per-lane)
static __device__ __forceinline__ void gl16(const void* g, void* l) {
    __builtin_amdgcn_global_load_lds(
        (const __attribute__((address_space(1))) void*)g,
        (__attribute__((address_space(3))) void*)l, 16, 0, 0);
}

// Fused prep: pack weights f32 [K=256][N] -> bf16 [N][256], qsum = bf16(query+qpos),
// and combined bias cb[384] = bo(256) || ba(128).
__global__ __launch_bounds__(256) void prep_k(
    const float* __restrict__ Wv, const float* __restrict__ Wo,
    const float* __restrict__ Wa, const float* __restrict__ Wout,
    const float* __restrict__ query, const float* __restrict__ qpos,
    const float* __restrict__ bo, const float* __restrict__ ba,
    bf16* __restrict__ Wv_p, bf16* __restrict__ Wo_p,
    bf16* __restrict__ Wa_p, bf16* __restrict__ Wout_p,
    bf16* __restrict__ qsum, float* __restrict__ cb)
{
    int bid = blockIdx.x, tid = threadIdx.x;
    if (bid < 896) {
        const float* src; bf16* dst; int N, t0;
        if (bid < 256)      { src = Wv;   dst = Wv_p;   N = 256; t0 = bid * 256; }
        else if (bid < 512) { src = Wo;   dst = Wo_p;   N = 256; t0 = (bid - 256) * 256; }
        else if (bid < 640) { src = Wa;   dst = Wa_p;   N = 128; t0 = (bid - 512) * 256; }
        else                { src = Wout; dst = Wout_p; N = 256; t0 = (bid - 640) * 256; }
        int t = t0 + tid;
        int n = t >> 8, k = t & 255;
        dst[t] = (bf16)src[k * N + n];
    } else if (bid < 10496) {
        int t = (bid - 896) * 256 + tid;
        qsum[t] = (bf16)(query[t] + qpos[t]);
    } else {
        cb[tid] = bo[tid];
        if (tid < 128) cb[256 + tid] = ba[tid];
    }
}

// v-GEMM v9 (B-frag REUSE): v[b][h][pix][32] = bf16(value @ Wv + bv). K=256.
// Tile = 128 rows/block, 4 waves x 2 strips of 16 rows: per kg(K=32) a wave
// reads 4 A + 16 B ds_read_b128 and issues 32 MFMA -> 0.63 ds_read/MFMA
// (3.2x fewer than the 64-row/1-strip structure that plateaued at ~99us, and
// half the per-byte vmcnt latency exposures). B LDS-resident 128KB (staged
// once); A wave-private K=32 chunks via contiguous gl16, double-buffered
// (32KB; total LDS = 160KB exactly); counted s_waitcnt vmcnt only, no loop
// barriers. Output layout [b][h][pix][32] for sample4 locality.
__global__ __launch_bounds__(256, 1) void vgemm_k(
    const float* __restrict__ A, const bf16* __restrict__ Bp,
    const float* __restrict__ bias, bf16* __restrict__ outB, int Mtiles)
{
    __shared__ __align__(16) bf16  sB[256 * 256];      // 128 KB
    __shared__ __align__(16) float sA[4 * 2 * 1024];   //  32 KB: [wave][buf][32r x 32]
    const int tid = threadIdx.x;
    const int lane = tid & 63;
    const int w = tid >> 6;
    const int l16 = lane & 15;
    const int qd = lane >> 4;

    // ---- one-time B stage: LDS slot p of row r holds global 16B chunk p^(r&7)
#pragma unroll
    for (int i = 0; i < 32; ++i) {
        int s = i * 256 + tid;
        int r = s >> 5, p = s & 31, c = p ^ (r & 7);
        gl16(Bp + (size_t)r * 256 + c * 8, sB + ((size_t)i * 256 + w * 64) * 8);
    }

    // ---- per-wave A chunk stage: 32 rows (w*32..+31) x 32 f32, 4 gl16 of 1KB.
    // gl16 #i covers rows i*8..i*8+7; lane l -> (row i*8 + (l>>3), slot l&7);
    // source pre-swizzled: global slot (l&7)^(row&7), row&7 = l>>3.
    float* sAw = sA + w * 2048;                 // 2 bufs x 1024 floats
    const int arow = lane >> 3;                 // row within 8-group = key
    const int aslot = (lane & 7) ^ arow;        // pre-swizzled global slot
    auto stageT = [&](int t_, int kg, int buf) {
        int b_ = t_ / TPB, p0_ = (t_ - b_ * TPB) * 128;
#pragma unroll
        for (int i = 0; i < 4; ++i) {
            int pix = min(p0_ + w * 32 + i * 8 + arow, NV - 1);
            gl16(A + ((size_t)b_ * NV + pix) * 256 + kg * 32 + aslot * 4,
                 sAw + buf * 1024 + i * 256);
        }
    };

    int t = blockIdx.x;
    stageT(t, 0, 0);
    stageT(t, 1, 1);

    float bb[16];
#pragma unroll
    for (int ct = 0; ct < 16; ++ct) bb[ct] = bias[ct * 16 + l16];

    __syncthreads();   // B resident; first two A chunks landed (vmcnt drained)

    const int akey = l16 & 7;
    f32x4 acc0[16], acc1[16];

    auto compute = [&](int kg, int buf) {
        const float* ab = sAw + buf * 1024;
        // strip A-frags: row = s*16 + l16 (stride 32 f32), slots (qd*2, qd*2+1)^akey
        const float* ar0 = ab + l16 * 32;
        const float* ar1 = ab + (16 + l16) * 32;
        float4 a00 = *(const float4*)(ar0 + ((qd * 2    ) ^ akey) * 4);
        float4 a01 = *(const float4*)(ar0 + ((qd * 2 + 1) ^ akey) * 4);
        float4 a10 = *(const float4*)(ar1 + ((qd * 2    ) ^ akey) * 4);
        float4 a11 = *(const float4*)(ar1 + ((qd * 2 + 1) ^ akey) * 4);
        bf16x8 af0 = cvt8(a00, a01);
        bf16x8 af1 = cvt8(a10, a11);
#pragma unroll
        for (int ct = 0; ct < 16; ++ct) {
            int brow = ct * 16 + l16;
            bf16x8 bfr = *(const bf16x8*)(sB + (size_t)brow * 256 +
                                          ((kg * 4 + qd) ^ (brow & 7)) * 8);
            acc0[ct] = __builtin_amdgcn_mfma_f32_16x16x32_bf16(af0, bfr, acc0[ct], 0, 0, 0);
            acc1[ct] = __builtin_amdgcn_mfma_f32_16x16x32_bf16(af1, bfr, acc1[ct], 0, 0, 0);
        }
    };

#define VM_WAIT4 asm volatile("s_waitcnt vmcnt(4)" ::: "memory")

    while (true) {
#pragma unroll
        for (int ct = 0; ct < 16; ++ct) {
            acc0[ct] = (f32x4){0.f, 0.f, 0.f, 0.f};
            acc1[ct] = (f32x4){0.f, 0.f, 0.f, 0.f};
        }

        int tn = t + gridDim.x;
        const bool last = (tn >= Mtiles);

        VM_WAIT4; compute(0, 0); stageT(t, 2, 0);
        VM_WAIT4; compute(1, 1); stageT(t, 3, 1);
        VM_WAIT4; compute(2, 0); stageT(t, 4, 0);
        VM_WAIT4; compute(3, 1); stageT(t, 5, 1);
        VM_WAIT4; compute(4, 0); stageT(t, 6, 0);
        VM_WAIT4; compute(5, 1); stageT(t, 7, 1);
        VM_WAIT4; compute(6, 0); if (!last) stageT(tn, 0, 0);
        VM_WAIT4; compute(7, 1); if (!last) stageT(tn, 1, 1);

        // epilogue: store to [b][h][pix][32]; h = ct>>1, d = (ct&1)*16 + l16
        int b = t / TPB, p0 = (t - b * TPB) * 128;
#pragma unroll
        for (int ct = 0; ct < 16; ++ct) {
            const bf16* dst0 = outB + ((size_t)(b * 8 + (ct >> 1)) * NV) * 32 + (ct & 1) * 16 + l16;
#pragma unroll
            for (int r = 0; r < 4; ++r) {
                int pix0 = p0 + w * 32 + qd * 4 + r;
                if (pix0 < NV)
                    *(bf16*)(dst0 + (size_t)pix0 * 32) = (bf16)(acc0[ct][r] + bb[ct]);
                int pix1 = pix0 + 16;
                if (pix1 < NV)
                    *(bf16*)(dst0 + (size_t)pix1 * 32) = (bf16)(acc1[ct][r] + bb[ct]);
            }
        }

        if (last) break;
        t = tn;
    }
#undef VM_WAIT4
}

// Small GEMM (M=9600): C = bf16A @ Bp^T (+bias)(+res). K=256. NGRP column
// groups of NB, B group in LDS staged once, A direct-to-reg 2-tile pipeline.
template <int NS, int NB, int NGRP, bool HAS_RES, bool OUT_BF16>
__global__ __launch_bounds__(256, 2) void gemm3_k(
    const bf16* __restrict__ Ah, const bf16* __restrict__ Bp,
    const float* __restrict__ bias, const float* __restrict__ res,
    float* __restrict__ outF, bf16* __restrict__ outB, int Mtiles)
{
    constexpr int CT = NB / 16;
    __shared__ __align__(16) bf16 sB[NB * 256];
    const int tid = threadIdx.x;
    const int lane = tid & 63;
    const int w = tid >> 6;
    const int l16 = lane & 15;
    const int qd = lane >> 4;
    const int col0 = (blockIdx.x % NGRP) * NB;
    const int tstride = gridDim.x / NGRP;
    const bf16* Bsrc = Bp + (size_t)col0 * 256;

    uint4 curH[8], nxtH[8];
    auto loadA = [&](int t, uint4* dH) {
        size_t rb = ((size_t)t * 64 + w * 16 + l16) * 256;
#pragma unroll
        for (int kc = 0; kc < 8; ++kc)
            dH[kc] = *(const uint4*)(Ah + rb + kc * 32 + qd * 8);
    };

    int tile = blockIdx.x / NGRP;
    if (tile < Mtiles) loadA(tile, curH);

#pragma unroll
    for (int i = 0; i < NB * 32 / 256; ++i) {
        int s = i * 256 + tid;
        int r = s >> 5, p = s & 31, c = p ^ (r & 7);
        gl16(Bsrc + (size_t)r * 256 + c * 8, sB + (size_t)(i * 256 + w * 64) * 8);
    }
    __syncthreads();

    for (; tile < Mtiles; tile += tstride) {
        int nt = tile + tstride;
        if (nt < Mtiles) loadA(nt, nxtH);

        f32x4 acc[CT];
#pragma unroll
        for (int c = 0; c < CT; ++c) acc[c] = (f32x4){0.f, 0.f, 0.f, 0.f};
#pragma unroll
        for (int kc = 0; kc < 8; ++kc) {
            bf16x8 af = *(const bf16x8*)&curH[kc];
#pragma unroll
            for (int ct = 0; ct < CT; ++ct) {
                int brow = ct * 16 + l16;
                int chunk = (kc * 4 + qd) ^ (l16 & 7);
                bf16x8 bfr = *(const bf16x8*)(sB + (size_t)brow * 256 + chunk * 8);
                acc[ct] = __builtin_amdgcn_mfma_f32_16x16x32_bf16(af, bfr, acc[ct], 0, 0, 0);
            }
        }
#pragma unroll
        for (int ct = 0; ct < CT; ++ct) {
            int col = col0 + ct * 16 + l16;
            float bbv = bias[col];
#pragma unroll
            for (int r = 0; r < 4; ++r) {
                int row = tile * 64 + w * 16 + qd * 4 + r;
                size_t idx = (size_t)row * NS + col;
                float v = acc[ct][r] + bbv;
                if (HAS_RES) v += res[(size_t)row * 256 + col];
                if (OUT_BF16) outB[idx] = (bf16)v;
                else          outF[idx] = v;
            }
        }
#pragma unroll
        for (int i = 0; i < 8; ++i) curH[i] = nxtH[i];
    }
}

static __device__ __forceinline__ void b8f(uint4 u, float* f) {
    f[0] = __uint_as_float(u.x << 16); f[1] = __uint_as_float(u.x & 0xffff0000u);
    f[2] = __uint_as_float(u.y << 16); f[3] = __uint_as_float(u.y & 0xffff0000u);
    f[4] = __uint_as_float(u.z << 16); f[5] = __uint_as_float(u.z & 0xffff0000u);
    f[6] = __uint_as_float(u.w << 16); f[7] = __uint_as_float(u.w & 0xffff0000u);
}

// Deformable sampling: ONE WAVE per (query,head). lane = (point p=lane>>2,
// channel-group dg=lane&3, 8 ch each). v layout [b][h][pix][32]: each corner
// is a 64B block, x-pairs contiguous 128B. off/attn read from fused comb
// buffer [9600][384] (off cols 0..255, attn cols 256..383).
__global__ __launch_bounds__(256) void sample4_k(
    const bf16* __restrict__ vv, const float* __restrict__ comb,
    const float* __restrict__ refp, const float* __restrict__ lref,
    bf16* __restrict__ outb)
{
    const int cH[4] = {92, 46, 23, 12};
    const int cW[4] = {160, 80, 40, 20};
    const int cS[4] = {0, 14720, 18400, 19320};
    const int w = threadIdx.x >> 6;
    const int lane = threadIdx.x & 63;
    const int wid = blockIdx.x * 4 + w;        // (bq, h)
    const int bq = wid >> 3, h = wid & 7;
    const int b = bq / NQ;
    const int p = lane >> 2, dg = lane & 3;
    const int lvl = p >> 2;

    // softmax over the 16 points of this (q,h): butterfly over p-lanes
    float logit = comb[(size_t)bq * 384 + 256 + h * 16 + p];
    float mx = logit;
#pragma unroll
    for (int s = 4; s < 64; s <<= 1) mx = fmaxf(mx, __shfl_xor(mx, s));
    float e = __expf(logit - mx);
    float ssum = e;
#pragma unroll
    for (int s = 4; s < 64; s <<= 1) ssum += __shfl_xor(ssum, s);
    float wgt = e / ssum;

    const int Hh = cH[lvl], Ww = cW[lvl];
    float ox = comb[(size_t)bq * 384 + h * 32 + p * 2];
    float oy = comb[(size_t)bq * 384 + h * 32 + p * 2 + 1];
    float rx = refp[(size_t)bq * 8 + lvl * 2];
    float ry = refp[(size_t)bq * 8 + lvl * 2 + 1];
    float lrx = lref[(size_t)bq * 16 + h * 2];
    float lry = lref[(size_t)bq * 16 + h * 2 + 1];

    float px = (rx + ox / (float)Ww + lrx) * (float)Ww - 0.5f;
    float py = (ry + oy / (float)Hh + lry) * (float)Hh - 0.5f;
    float x0f = floorf(px), y0f = floorf(py);
    int x0 = (int)x0f, y0 = (int)y0f;
    float wx1 = px - x0f, wx0 = 1.f - wx1;
    float wy1 = py - y0f, wy0 = 1.f - wy1;
    bool xa = (unsigned)x0 < (unsigned)Ww, xb = (unsigned)(x0 + 1) < (unsigned)Ww;
    bool ya = (unsigned)y0 < (unsigned)Hh, yb = (unsigned)(y0 + 1) < (unsigned)Hh;
    int xc0 = min(max(x0, 0), Ww - 1), xc1 = min(max(x0 + 1, 0), Ww - 1);
    int yc0 = min(max(y0, 0), Hh - 1), yc1 = min(max(y0 + 1, 0), Hh - 1);
    float w00 = wgt * wx0 * wy0 * (float)(xa && ya);
    float w01 = wgt * wx1 * wy0 * (float)(xb && ya);
    float w10 = wgt * wx0 * wy1 * (float)(xa && yb);
    float w11 = wgt * wx1 * wy1 * (float)(xb && yb);

    const bf16* vb = vv + ((size_t)(b * 8 + h) * NV + cS[lvl]) * 32 + dg * 8;
    uint4 g00 = *(const uint4*)(vb + ((size_t)yc0 * Ww + xc0) * 32);
    uint4 g01 = *(const uint4*)(vb + ((size_t)yc0 * Ww + xc1) * 32);
    uint4 g10 = *(const uint4*)(vb + ((size_t)yc1 * Ww + xc0) * 32);
    uint4 g11 = *(const uint4*)(vb + ((size_t)yc1 * Ww + xc1) * 32);

    float acc[8], f[8];
    b8f(g00, f);
#pragma unroll
    for (int j = 0; j < 8; j++) acc[j] = w00 * f[j];
    b8f(g01, f);
#pragma unroll
    for (int j = 0; j < 8; j++) acc[j] = fmaf(w01, f[j], acc[j]);
    b8f(g10, f);
#pragma unroll
    for (int j = 0; j < 8; j++) acc[j] = fmaf(w10, f[j], acc[j]);
    b8f(g11, f);
#pragma unroll
    for (int j = 0; j < 8; j++) acc[j] = fmaf(w11, f[j], acc[j]);

    // sum over the 16 points (p-lanes): butterfly
#pragma unroll
    for (int s = 4; s < 64; s <<= 1)
#pragma unroll
        for (int j = 0; j < 8; j++) acc[j] += __shfl_xor(acc[j], s);

    if (p == 0) {
        bf16x8 o;
#pragma unroll
        for (int j = 0; j < 8; j++) o[j] = (bf16)acc[j];
        *(bf16x8*)(outb + (size_t)bq * 256 + h * 32 + dg * 8) = o;
    }
}

extern "C" void kernel_launch(void* const* d_in, const int* in_sizes, int n_in,
                              void* d_out, int out_size, void* d_ws, size_t ws_size,
                              hipStream_t stream) {
    (void)in_sizes; (void)n_in; (void)out_size; (void)ws_size;
    const float* query = (const float*)d_in[0];
    const float* value = (const float*)d_in[1];
    const float* qpos  = (const float*)d_in[2];
    const float* refp  = (const float*)d_in[3];
    const float* lref  = (const float*)d_in[4];
    const float* Wv   = (const float*)d_in[6];
    const float* bv   = (const float*)d_in[7];
    const float* Wo   = (const float*)d_in[8];
    const float* bo   = (const float*)d_in[9];
    const float* Wa   = (const float*)d_in[10];
    const float* ba   = (const float*)d_in[11];
    const float* Wout = (const float*)d_in[12];
    const float* bout = (const float*)d_in[13];

    char* ws = (char*)d_ws;
    bf16*  Wv_p   = (bf16*)(ws + 0);          //   131,072
    bf16*  Wo_p   = (bf16*)(ws + 131072);     //   131,072  (Wo_p||Wa_p contiguous = packed [384][256])
    bf16*  Wa_p   = (bf16*)(ws + 262144);     //    65,536
    bf16*  Wout_p = (bf16*)(ws + 327680);     //   131,072
    bf16*  qsum   = (bf16*)(ws + 458752);     // 4,915,200
    float* comb   = (float*)(ws + 5373952);   // 14,745,600 (off|attn fused, [9600][384])
    bf16*  tsa_b  = (bf16*)(ws + 20119552);   // 4,915,200
    bf16*  v_b    = (bf16*)(ws + 25034752);   // 80,117,760 ([b][h][NV][32])
    float* cbias  = (float*)(ws + 105152512); //      1,536

    prep_k<<<10497, 256, 0, stream>>>(Wv, Wo, Wa, Wout, query, qpos, bo, ba,
                                      Wv_p, Wo_p, Wa_p, Wout_p, qsum, cbias);

    // v[b][h][pix][32] = value @ Wv + bv (bf16): 1224 128-row tiles, 256 blocks
    vgemm_k<<<256, 256, 0, stream>>>(value, Wv_p, bv, v_b, BS * TPB);
    // comb = qsum @ [Wo|Wa] + [bo|ba] (f32, N=384): 3 col groups x 150 tiles
    gemm3_k<384, 128, 3, false, false><<<450, 256, 0, stream>>>(
        qsum, Wo_p, cbias, nullptr, comb, nullptr, (BS * NQ) / 64);
    // deformable sampling -> tsa (bf16): one wave per (q,h)
    sample4_k<<<(BS * NQ * 8) / 4, 256, 0, stream>>>(v_b, comb, refp, lref, tsa_b);
    // out = tsa @ Wout + bout + query (f32)
    gemm3_k<256, 128, 2, true, false><<<300, 256, 0, stream>>>(
        tsa_b, Wout_p, bout, query, (float*)d_out, nullptr, (BS * NQ) / 64);
}

// Round 8
// 393.185 us; speedup vs baseline: 1.0083x; 1.0083x over previous
//
#include <hip/hip_runtime.h>
#include <math.h>

#define BS 8
#define NQ 1200
#define NV 19560
#define NVP 19584               // padded pix stride for v_b (= TPB*128)
#define EMB 256
#define TPB 153                 // 128-row tiles per batch

typedef __bf16 bf16;
typedef bf16 bf16x8 __attribute__((ext_vector_type(8)));
typedef bf16 bf16x4 __attribute__((ext_vector_type(4)));
typedef float f32x4 __attribute__((ext_vector_type(4)));

static __device__ __forceinline__ bf16x8 cvt8(float4 a, float4 b) {
    bf16x8 r;
    r[0] = (bf16)a.x; r[1] = (bf16)a.y; r[2] = (bf16)a.z; r[3] = (bf16)a.w;
    r[4] = (bf16)b.x; r[5] = (bf16)b.y; r[6] = (bf16)b.z; r[7] = (bf16)b.w;
    return r;
}

// async 16B global -> LDS (wave-uniform LDS base + lane*16 in HW; global src per-lane)
static __device__ __forceinline__ void gl16(const void* g, void* l) {
    __builtin_amdgcn_global_load_lds(
        (const __attribute__((address_space(1))) void*)g,
        (__attribute__((address_space(3))) void*)l, 16, 0, 0);
}

// Fused prep: pack weights f32 [K=256][N] -> bf16 [N][256], qsum = bf16(query+qpos),
// and combined bias cb[384] = bo(256) || ba(128).
__global__ __launch_bounds__(256) void prep_k(
    const float* __restrict__ Wv, const float* __restrict__ Wo,
    const float* __restrict__ Wa, const float* __restrict__ Wout,
    const float* __restrict__ query, const float* __restrict__ qpos,
    const float* __restrict__ bo, const float* __restrict__ ba,
    bf16* __restrict__ Wv_p, bf16* __restrict__ Wo_p,
    bf16* __restrict__ Wa_p, bf16* __restrict__ Wout_p,
    bf16* __restrict__ qsum, float* __restrict__ cb)
{
    int bid = blockIdx.x, tid = threadIdx.x;
    if (bid < 896) {
        const float* src; bf16* dst; int N, t0;
        if (bid < 256)      { src = Wv;   dst = Wv_p;   N = 256; t0 = bid * 256; }
        else if (bid < 512) { src = Wo;   dst = Wo_p;   N = 256; t0 = (bid - 256) * 256; }
        else if (bid < 640) { src = Wa;   dst = Wa_p;   N = 128; t0 = (bid - 512) * 256; }
        else                { src = Wout; dst = Wout_p; N = 256; t0 = (bid - 640) * 256; }
        int t = t0 + tid;
        int n = t >> 8, k = t & 255;
        dst[t] = (bf16)src[k * N + n];
    } else if (bid < 10496) {
        int t = (bid - 896) * 256 + tid;
        qsum[t] = (bf16)(query[t] + qpos[t]);
    } else {
        cb[tid] = bo[tid];
        if (tid < 128) cb[256 + tid] = ba[tid];
    }
}

// v-GEMM v10 (swapped-operand epilogue): v[b][h][pix(NVP)][32] = bf16(value@Wv+bv).
// Same load/compute machinery as R7 (B LDS-resident 128KB staged once; A
// wave-private K=32 chunk double-buffer via gl16; counted vmcnt; no loop
// barriers). CHANGE: mfma(W_frag, A_frag) -- operand layouts are symmetric so
// loads are identical, but C/D transposes: lane&15 = pix, qd*4+reg = channel.
// Epilogue packs 4 consecutive channels -> bf16x4: 32 dwordx2 stores/wave-tile
// instead of 128 scalar-bf16 (4x fewer vmcnt entries). Stores UNGUARDED into
// padded pix-dim (NVP) -> constant store count -> first two tile waits can be
// vmcnt(36) (wait ONLY the 4 oldest loads, not the store queue). Bias folded
// into acc-init.
__global__ __launch_bounds__(256, 1) void vgemm_k(
    const float* __restrict__ A, const bf16* __restrict__ Bp,
    const float* __restrict__ bias, bf16* __restrict__ outB, int Mtiles)
{
    __shared__ __align__(16) bf16  sB[256 * 256];      // 128 KB
    __shared__ __align__(16) float sA[4 * 2 * 1024];   //  32 KB: [wave][buf][32r x 32]
    const int tid = threadIdx.x;
    const int lane = tid & 63;
    const int w = tid >> 6;
    const int l16 = lane & 15;
    const int qd = lane >> 4;

    // ---- one-time B stage: LDS slot p of row r holds global 16B chunk p^(r&7)
#pragma unroll
    for (int i = 0; i < 32; ++i) {
        int s = i * 256 + tid;
        int r = s >> 5, p = s & 31, c = p ^ (r & 7);
        gl16(Bp + (size_t)r * 256 + c * 8, sB + ((size_t)i * 256 + w * 64) * 8);
    }

    // ---- per-wave A chunk stage: 32 rows (w*32..+31) x 32 f32, 4 gl16 of 1KB.
    float* sAw = sA + w * 2048;                 // 2 bufs x 1024 floats
    const int arow = lane >> 3;                 // row within 8-group = swizzle key
    const int aslot = (lane & 7) ^ arow;        // pre-swizzled global 16B slot
    auto stageT = [&](int t_, int kg, int buf) {
        int b_ = t_ / TPB, p0_ = (t_ - b_ * TPB) * 128;
#pragma unroll
        for (int i = 0; i < 4; ++i) {
            int pix = min(p0_ + w * 32 + i * 8 + arow, NV - 1);
            gl16(A + ((size_t)b_ * NV + pix) * 256 + kg * 32 + aslot * 4,
                 sAw + buf * 1024 + i * 256);
        }
    };

    int t = blockIdx.x;
    stageT(t, 0, 0);
    stageT(t, 1, 1);

    // bias folded into acc init: channels ct*16 + qd*4 .. +3
    f32x4 bias4[16];
#pragma unroll
    for (int ct = 0; ct < 16; ++ct)
        bias4[ct] = *(const f32x4*)(bias + ct * 16 + qd * 4);

    __syncthreads();   // B resident; first two A chunks landed (vmcnt drained)

    const int akey = l16 & 7;
    f32x4 acc0[16], acc1[16];

    auto compute = [&](int kg, int buf) {
        const float* ab = sAw + buf * 1024;
        const float* ar0 = ab + l16 * 32;
        const float* ar1 = ab + (16 + l16) * 32;
        float4 a00 = *(const float4*)(ar0 + ((qd * 2    ) ^ akey) * 4);
        float4 a01 = *(const float4*)(ar0 + ((qd * 2 + 1) ^ akey) * 4);
        float4 a10 = *(const float4*)(ar1 + ((qd * 2    ) ^ akey) * 4);
        float4 a11 = *(const float4*)(ar1 + ((qd * 2 + 1) ^ akey) * 4);
        bf16x8 af0 = cvt8(a00, a01);
        bf16x8 af1 = cvt8(a10, a11);
#pragma unroll
        for (int ct = 0; ct < 16; ++ct) {
            int brow = ct * 16 + l16;
            bf16x8 bfr = *(const bf16x8*)(sB + (size_t)brow * 256 +
                                          ((kg * 4 + qd) ^ (brow & 7)) * 8);
            // swapped operands: D[m=channel][n=pix]
            acc0[ct] = __builtin_amdgcn_mfma_f32_16x16x32_bf16(bfr, af0, acc0[ct], 0, 0, 0);
            acc1[ct] = __builtin_amdgcn_mfma_f32_16x16x32_bf16(bfr, af1, acc1[ct], 0, 0, 0);
        }
    };

#define VM_WAIT36 asm volatile("s_waitcnt vmcnt(36)" ::: "memory")
#define VM_WAIT4  asm volatile("s_waitcnt vmcnt(4)"  ::: "memory")

    while (true) {
#pragma unroll
        for (int ct = 0; ct < 16; ++ct) { acc0[ct] = bias4[ct]; acc1[ct] = bias4[ct]; }

        int tn = t + gridDim.x;
        const bool last = (tn >= Mtiles);

        // queue at loop top (steady): [tn0 x4][tn1 x4][32 stores] -> vmcnt(36)
        // waits only the 4 oldest loads (store count is constant: unguarded).
        VM_WAIT36; compute(0, 0); stageT(t, 2, 0);
        VM_WAIT36; compute(1, 1); stageT(t, 3, 1);
        VM_WAIT4;  compute(2, 0); stageT(t, 4, 0);
        VM_WAIT4;  compute(3, 1); stageT(t, 5, 1);
        VM_WAIT4;  compute(4, 0); stageT(t, 6, 0);
        VM_WAIT4;  compute(5, 1); stageT(t, 7, 1);
        VM_WAIT4;  compute(6, 0); if (!last) stageT(tn, 0, 0);
        VM_WAIT4;  compute(7, 1); if (!last) stageT(tn, 1, 1);

        // epilogue: lane (qd,l16) holds channels ct*16+qd*4..+3 of pix strip+l16.
        // 32 x 8B packed stores into padded [b][h][NVP][32] (unguarded).
        int b = t / TPB, p0 = (t - b * TPB) * 128;
        int pix0 = p0 + w * 32 + l16;
#pragma unroll
        for (int ct = 0; ct < 16; ++ct) {
            bf16* dst = outB + ((size_t)(b * 8 + (ct >> 1)) * NVP) * 32
                             + (ct & 1) * 16 + qd * 4;
            bf16x4 v0, v1;
#pragma unroll
            for (int r = 0; r < 4; ++r) { v0[r] = (bf16)acc0[ct][r]; v1[r] = (bf16)acc1[ct][r]; }
            *(bf16x4*)(dst + (size_t)pix0 * 32)        = v0;
            *(bf16x4*)(dst + (size_t)(pix0 + 16) * 32) = v1;
        }

        if (last) break;
        t = tn;
    }
#undef VM_WAIT36
#undef VM_WAIT4
}

// Small GEMM (M=9600): C = bf16A @ Bp^T (+bias)(+res). K=256. NGRP column
// groups of NB, B group in LDS staged once, A direct-to-reg 2-tile pipeline.
template <int NS, int NB, int NGRP, bool HAS_RES, bool OUT_BF16>
__global__ __launch_bounds__(256, 2) void gemm3_k(
    const bf16* __restrict__ Ah, const bf16* __restrict__ Bp,
    const float* __restrict__ bias, const float* __restrict__ res,
    float* __restrict__ outF, bf16* __restrict__ outB, int Mtiles)
{
    constexpr int CT = NB / 16;
    __shared__ __align__(16) bf16 sB[NB * 256];
    const int tid = threadIdx.x;
    const int lane = tid & 63;
    const int w = tid >> 6;
    const int l16 = lane & 15;
    const int qd = lane >> 4;
    const int col0 = (blockIdx.x % NGRP) * NB;
    const int tstride = gridDim.x / NGRP;
    const bf16* Bsrc = Bp + (size_t)col0 * 256;

    uint4 curH[8], nxtH[8];
    auto loadA = [&](int t, uint4* dH) {
        size_t rb = ((size_t)t * 64 + w * 16 + l16) * 256;
#pragma unroll
        for (int kc = 0; kc < 8; ++kc)
            dH[kc] = *(const uint4*)(Ah + rb + kc * 32 + qd * 8);
    };

    int tile = blockIdx.x / NGRP;
    if (tile < Mtiles) loadA(tile, curH);

#pragma unroll
    for (int i = 0; i < NB * 32 / 256; ++i) {
        int s = i * 256 + tid;
        int r = s >> 5, p = s & 31, c = p ^ (r & 7);
        gl16(Bsrc + (size_t)r * 256 + c * 8, sB + (size_t)(i * 256 + w * 64) * 8);
    }
    __syncthreads();

    for (; tile < Mtiles; tile += tstride) {
        int nt = tile + tstride;
        if (nt < Mtiles) loadA(nt, nxtH);

        f32x4 acc[CT];
#pragma unroll
        for (int c = 0; c < CT; ++c) acc[c] = (f32x4){0.f, 0.f, 0.f, 0.f};
#pragma unroll
        for (int kc = 0; kc < 8; ++kc) {
            bf16x8 af = *(const bf16x8*)&curH[kc];
#pragma unroll
            for (int ct = 0; ct < CT; ++ct) {
                int brow = ct * 16 + l16;
                int chunk = (kc * 4 + qd) ^ (l16 & 7);
                bf16x8 bfr = *(const bf16x8*)(sB + (size_t)brow * 256 + chunk * 8);
                acc[ct] = __builtin_amdgcn_mfma_f32_16x16x32_bf16(af, bfr, acc[ct], 0, 0, 0);
            }
        }
#pragma unroll
        for (int ct = 0; ct < CT; ++ct) {
            int col = col0 + ct * 16 + l16;
            float bbv = bias[col];
#pragma unroll
            for (int r = 0; r < 4; ++r) {
                int row = tile * 64 + w * 16 + qd * 4 + r;
                size_t idx = (size_t)row * NS + col;
                float v = acc[ct][r] + bbv;
                if (HAS_RES) v += res[(size_t)row * 256 + col];
                if (OUT_BF16) outB[idx] = (bf16)v;
                else          outF[idx] = v;
            }
        }
#pragma unroll
        for (int i = 0; i < 8; ++i) curH[i] = nxtH[i];
    }
}

static __device__ __forceinline__ void b8f(uint4 u, float* f) {
    f[0] = __uint_as_float(u.x << 16); f[1] = __uint_as_float(u.x & 0xffff0000u);
    f[2] = __uint_as_float(u.y << 16); f[3] = __uint_as_float(u.y & 0xffff0000u);
    f[4] = __uint_as_float(u.z << 16); f[5] = __uint_as_float(u.z & 0xffff0000u);
    f[6] = __uint_as_float(u.w << 16); f[7] = __uint_as_float(u.w & 0xffff0000u);
}

// Deformable sampling v2 (x-pair gathers): ONE WAVE per (query,head).
// lane = (ps=lane>>3: point-in-set, dg8=lane&7: 16B chunk of the 128B x-pair).
// Two passes cover 16 points. Per pass each lane loads the y0-row and y1-row
// x-pair chunks (contiguous 128B blocks -> ~1.6x fewer cache lines than 4
// separate 64B corners). Pair base px0=clamp(x0,0,W-2); per-half weight picks
// wx0/wx1/0 so zero-padding semantics match the reference. Softmax on 2
// logits/lane + ps-butterfly; final sum over bits 2..5.
__global__ __launch_bounds__(256) void sample4_k(
    const bf16* __restrict__ vv, const float* __restrict__ comb,
    const float* __restrict__ refp, const float* __restrict__ lref,
    bf16* __restrict__ outb)
{
    const int cH[4] = {92, 46, 23, 12};
    const int cW[4] = {160, 80, 40, 20};
    const int cS[4] = {0, 14720, 18400, 19320};
    const int w = threadIdx.x >> 6;
    const int lane = threadIdx.x & 63;
    const int wid = blockIdx.x * 4 + w;        // (bq, h)
    const int bq = wid >> 3, h = wid & 7;
    const int b = bq / NQ;
    const int ps = lane >> 3;                  // point within set (0..7)
    const int dg8 = lane & 7;                  // 16B chunk in 128B pair
    const int hx2 = dg8 >> 2;                  // which pixel of the pair

    // softmax over 16 points: two logits per lane + butterfly over ps bits
    float lg0 = comb[(size_t)bq * 384 + 256 + h * 16 + ps];
    float lg1 = comb[(size_t)bq * 384 + 256 + h * 16 + 8 + ps];
    float mx = fmaxf(lg0, lg1);
#pragma unroll
    for (int s = 8; s < 64; s <<= 1) mx = fmaxf(mx, __shfl_xor(mx, s));
    float e0 = __expf(lg0 - mx), e1 = __expf(lg1 - mx);
    float ss = e0 + e1;
#pragma unroll
    for (int s = 8; s < 64; s <<= 1) ss += __shfl_xor(ss, s);
    float inv = 1.f / ss;

    float acc[8];
#pragma unroll
    for (int j = 0; j < 8; j++) acc[j] = 0.f;

    const float* rp = refp + (size_t)bq * 8;
    float lrx = lref[(size_t)bq * 16 + h * 2];
    float lry = lref[(size_t)bq * 16 + h * 2 + 1];

#pragma unroll
    for (int s2 = 0; s2 < 2; ++s2) {
        int p = s2 * 8 + ps;
        int lvl = p >> 2;
        const int Hh = cH[lvl], Ww = cW[lvl];
        float ox = comb[(size_t)bq * 384 + h * 32 + p * 2];
        float oy = comb[(size_t)bq * 384 + h * 32 + p * 2 + 1];
        float rx = rp[lvl * 2], ry = rp[lvl * 2 + 1];

        float px = (rx + ox / (float)Ww + lrx) * (float)Ww - 0.5f;
        float py = (ry + oy / (float)Hh + lry) * (float)Hh - 0.5f;
        float x0f = floorf(px), y0f = floorf(py);
        int x0 = (int)x0f, y0 = (int)y0f;
        float wx1 = px - x0f, wx0 = 1.f - wx1;
        float wy1 = py - y0f, wy0 = 1.f - wy1;
        bool xa = (unsigned)x0 < (unsigned)Ww, xb = (unsigned)(x0 + 1) < (unsigned)Ww;
        bool ya = (unsigned)y0 < (unsigned)Hh, yb = (unsigned)(y0 + 1) < (unsigned)Hh;
        int px0 = min(max(x0, 0), Ww - 2);
        int hx = px0 + hx2;                     // the pixel this lane-half holds
        float wxh = (hx == x0 && xa) ? wx0 : ((hx == x0 + 1 && xb) ? wx1 : 0.f);
        int yc0 = min(max(y0, 0), Hh - 1), yc1 = min(max(y0 + 1, 0), Hh - 1);
        float wgt = (s2 ? e1 : e0) * inv;
        float wA = wgt * wy0 * (ya ? 1.f : 0.f) * wxh;
        float wB = wgt * wy1 * (yb ? 1.f : 0.f) * wxh;

        const bf16* base = vv + ((size_t)(b * 8 + h) * NVP + cS[lvl]) * 32 + dg8 * 8;
        uint4 gA = *(const uint4*)(base + ((size_t)yc0 * Ww + px0) * 32);
        uint4 gB = *(const uint4*)(base + ((size_t)yc1 * Ww + px0) * 32);

        float f[8];
        b8f(gA, f);
#pragma unroll
        for (int j = 0; j < 8; j++) acc[j] = fmaf(wA, f[j], acc[j]);
        b8f(gB, f);
#pragma unroll
        for (int j = 0; j < 8; j++) acc[j] = fmaf(wB, f[j], acc[j]);
    }

    // sum over bits 2..5 (pair-half + 8 points)
#pragma unroll
    for (int s = 4; s < 64; s <<= 1)
#pragma unroll
        for (int j = 0; j < 8; j++) acc[j] += __shfl_xor(acc[j], s);

    if (lane < 4) {
        bf16x8 o;
#pragma unroll
        for (int j = 0; j < 8; j++) o[j] = (bf16)acc[j];
        *(bf16x8*)(outb + (size_t)bq * 256 + h * 32 + lane * 8) = o;
    }
}

extern "C" void kernel_launch(void* const* d_in, const int* in_sizes, int n_in,
                              void* d_out, int out_size, void* d_ws, size_t ws_size,
                              hipStream_t stream) {
    (void)in_sizes; (void)n_in; (void)out_size; (void)ws_size;
    const float* query = (const float*)d_in[0];
    const float* value = (const float*)d_in[1];
    const float* qpos  = (const float*)d_in[2];
    const float* refp  = (const float*)d_in[3];
    const float* lref  = (const float*)d_in[4];
    const float* Wv   = (const float*)d_in[6];
    const float* bv   = (const float*)d_in[7];
    const float* Wo   = (const float*)d_in[8];
    const float* bo   = (const float*)d_in[9];
    const float* Wa   = (const float*)d_in[10];
    const float* ba   = (const float*)d_in[11];
    const float* Wout = (const float*)d_in[12];
    const float* bout = (const float*)d_in[13];

    char* ws = (char*)d_ws;
    bf16*  Wv_p   = (bf16*)(ws + 0);          //   131,072
    bf16*  Wo_p   = (bf16*)(ws + 131072);     //   131,072  (Wo_p||Wa_p = packed [384][256])
    bf16*  Wa_p   = (bf16*)(ws + 262144);     //    65,536
    bf16*  Wout_p = (bf16*)(ws + 327680);     //   131,072
    bf16*  qsum   = (bf16*)(ws + 458752);     // 4,915,200
    float* comb   = (float*)(ws + 5373952);   // 14,745,600 (off|attn fused, [9600][384])
    bf16*  tsa_b  = (bf16*)(ws + 20119552);   // 4,915,200
    bf16*  v_b    = (bf16*)(ws + 25034752);   // 80,216,064 ([b][h][NVP][32], padded)
    float* cbias  = (float*)(ws + 105250816); //      1,536

    prep_k<<<10497, 256, 0, stream>>>(Wv, Wo, Wa, Wout, query, qpos, bo, ba,
                                      Wv_p, Wo_p, Wa_p, Wout_p, qsum, cbias);

    // v[b][h][pix][32] = value @ Wv + bv (bf16): 1224 128-row tiles, 256 blocks
    vgemm_k<<<256, 256, 0, stream>>>(value, Wv_p, bv, v_b, BS * TPB);
    // comb = qsum @ [Wo|Wa] + [bo|ba] (f32, N=384): 3 col groups x 150 tiles
    gemm3_k<384, 128, 3, false, false><<<450, 256, 0, stream>>>(
        qsum, Wo_p, cbias, nullptr, comb, nullptr, (BS * NQ) / 64);
    // deformable sampling -> tsa (bf16): one wave per (q,h), x-pair gathers
    sample4_k<<<(BS * NQ * 8) / 4, 256, 0, stream>>>(v_b, comb, refp, lref, tsa_b);
    // out = tsa @ Wout + bout + query (f32)
    gemm3_k<256, 128, 2, true, false><<<300, 256, 0, stream>>>(
        tsa_b, Wout_p, bout, query, (float*)d_out, nullptr, (BS * NQ) / 64);
}